// Round 1
// 421.715 us; speedup vs baseline: 1.0335x; 1.0335x over previous
//
#include <hip/hip_runtime.h>

// CoreSageLayer: x1 = (adj @ x)/deg ; out[k] = [x1|x] @ W[k] + bias, k=0..2
// N=8192, F=256, OUT=256. adj int32 in {0,1} (256 MB, the HBM floor).
//
// Strategy (this round: pipelined phase1, fused conversion pre-pass):
//  - bf16 MFMA (16x16x32). adj->bf16 is exact (0/1 -> 0x0000/0x3F80 bit trick).
//  - "Fragment-major" bf16 layouts in workspace: 16B chunks = one lane's 8
//    contiguous-k elements; B/A operands load directly global->VGPR as ready
//    MFMA frags (coalesced, L2-resident).
//  - conv_all: single kernel doing all 3 layout conversions (block-range split).
//  - Phase1: 256 blocks x 1024 thr; 4 K-split groups (4 waves each, M-tile 32,
//    full N=256/group). SOFTWARE-PIPELINED: adj tile for step s+2 issued into
//    registers (two named sets, unroll-2) while step s computes; convert+LDS
//    write of the *arrived* step s+1 happens after the MFMAs (vmcnt wait hits
//    loads issued a full step earlier -> no stall); double-buffered LDS A, one
//    barrier per step (was two + exposed ~900cy HBM latency every step).
//  - Phase2: zero-LDS register GEMM M=8192 K=512 N=768, bias add, nt stores.

typedef unsigned short u16;
typedef int   i32x4 __attribute__((ext_vector_type(4)));
typedef unsigned u32x4 __attribute__((ext_vector_type(4)));
typedef float f32x4 __attribute__((ext_vector_type(4)));

__device__ __forceinline__ u16 f2b(float f) {  // fp32 -> bf16 RNE
  unsigned u = __builtin_bit_cast(unsigned, f);
  return (u16)((u + 0x7FFFu + ((u >> 16) & 1u)) >> 16);
}
__device__ __forceinline__ unsigned pack2(float a, float b) {
  return (unsigned)f2b(a) | ((unsigned)f2b(b) << 16);
}
__device__ __forceinline__ f32x4 mfma16(u32x4 a, u32x4 b, f32x4 c) {
  // D = A(16x32) * B(32x16) + C, bf16 inputs. A: lane m=l&15,k=(l>>4)*8+j.
  // B: lane n=l&15,k=(l>>4)*8+j. C/D: col=l&15,row=(l>>4)*4+reg.
  asm("v_mfma_f32_16x16x32_bf16 %0, %1, %2, %0" : "+v"(c) : "v"(a), "v"(b));
  return c;
}

// ---- fused pre-pass: all three bf16 frag-major conversions in one launch.
// blocks [0,1024):    xtf  : chunk c = kc8*256 + f holds x[kc8*8+jj][f]. (4 MB)
// blocks [1024,2048): nxtf : x half of n_x, chunk = (32+(f>>3))*8192 + m. (8 MB arr)
// blocks [2048,2240): wtf  : chunk = kc8*768 + (kk*256+o). (768 KB)
__global__ __launch_bounds__(256) void conv_all(const float* __restrict__ x,
                                                const float* __restrict__ w,
                                                u16* __restrict__ xtf,
                                                u16* __restrict__ nxtf,
                                                u16* __restrict__ wtf) {
  const int b = blockIdx.x;
  if (b < 1024) {
    int c = b * 256 + threadIdx.x;            // 0..262143
    int kc8 = c >> 8, f = c & 255;
    const float* p = x + (size_t)kc8 * 2048 + f;
    u32x4 h;
    h.x = pack2(p[0],    p[256]);
    h.y = pack2(p[512],  p[768]);
    h.z = pack2(p[1024], p[1280]);
    h.w = pack2(p[1536], p[1792]);
    *(u32x4*)(xtf + (size_t)c * 8) = h;
  } else if (b < 2048) {
    int c = (b - 1024) * 256 + threadIdx.x;   // 0..262143
    int kc8r = c >> 13, m = c & 8191;
    const float* p = x + (size_t)m * 256 + kc8r * 8;
    f32x4 p0 = *(const f32x4*)p;
    f32x4 p1 = *(const f32x4*)(p + 4);
    u32x4 h;
    h.x = pack2(p0.x, p0.y); h.y = pack2(p0.z, p0.w);
    h.z = pack2(p1.x, p1.y); h.w = pack2(p1.z, p1.w);
    *(u32x4*)(nxtf + ((size_t)(32 + kc8r) * 8192 + m) * 8) = h;
  } else {
    int idx = (b - 2048) * 256 + threadIdx.x; // 0..49151
    int kc8 = idx / 768;                      // 0..63
    int c = idx - kc8 * 768;                  // 0..767
    int kk = c >> 8, o = c & 255;
    const float* p = w + (size_t)kk * 131072 + (size_t)kc8 * 2048 + o;
    u32x4 h;
    h.x = pack2(p[0],    p[256]);
    h.y = pack2(p[512],  p[768]);
    h.z = pack2(p[1024], p[1280]);
    h.w = pack2(p[1536], p[1792]);
    *(u32x4*)(wtf + (size_t)idx * 8) = h;
  }
}

// ---- phase 1: S = adj @ x (bf16 MFMA), deg fused, x1 = S/deg -> nxtf[k<256]
// Pipelined: reg-prefetch adj(s+2), compute(s) from LDS buf[s&1], then convert
// the arrived adj(s+1) into the other buffer. 1 barrier/step, no exposed vmcnt.
__global__ __launch_bounds__(1024) void phase1(const int* __restrict__ adj,
                                               const u16* __restrict__ xtf,
                                               u16* __restrict__ nxtf) {
  __shared__ __align__(16) u16 AsmF[2][4 * 32 * 72];  // dbuf x 4 groups x [32][64+8 pad]
  __shared__ float Csum[32 * 260];                    // combine buffer
  __shared__ int degs[1024];
  __shared__ float degrow[32];

  const int t  = threadIdx.x;
  const int g  = t >> 8;          // K-split group 0..3
  const int lt = t & 255;         // thread within group
  const int l  = t & 63;          // lane
  const int w4 = lt >> 6;         // wave within group -> 64-col N strip
  const int l15 = l & 15, l16 = l >> 4;
  const int m0 = blockIdx.x * 32;
  const int r = lt >> 3, kq = lt & 7;  // staging: row r, 8-k quad kq

  f32x4 acc[2][4] = {};
  int dsum = 0;

  const int* arow = adj + (size_t)(m0 + r) * 8192 + g * 2048 + kq * 8;
  u16* const stp0 = &AsmF[0][(g * 32 + r) * 72 + kq * 8];
  u16* const stp1 = &AsmF[1][(g * 32 + r) * 72 + kq * 8];
  const int afrag0 = (g * 32 + l15) * 72 + l16 * 8;
  const u16* bbase = xtf + (size_t)l16 * 2048 + (size_t)(w4 * 64 + l15) * 8;

  auto LOADA = [&](i32x4& d0, i32x4& d1, int s) {
    d0 = __builtin_nontemporal_load((const i32x4*)(arow + s * 64));
    d1 = __builtin_nontemporal_load((const i32x4*)(arow + s * 64) + 1);
  };
  auto CONVST = [&](i32x4 p0, i32x4 p1, u16* stp) {
    dsum += p0.x + p0.y + p0.z + p0.w + p1.x + p1.y + p1.z + p1.w;
    u32x4 h;
    h.x = (p0.x ? 0x3F80u : 0u) | (p0.y ? 0x3F800000u : 0u);
    h.y = (p0.z ? 0x3F80u : 0u) | (p0.w ? 0x3F800000u : 0u);
    h.z = (p1.x ? 0x3F80u : 0u) | (p1.y ? 0x3F800000u : 0u);
    h.w = (p1.z ? 0x3F80u : 0u) | (p1.w ? 0x3F800000u : 0u);
    *(u32x4*)stp = h;
  };
  auto COMPUTE = [&](int s, int buf) {
    const u16* bstep = bbase + ((size_t)(g * 2048 + s * 64) << 8);
#pragma unroll
    for (int kc = 0; kc < 2; ++kc) {
      u32x4 a0 = *(const u32x4*)&AsmF[buf][afrag0 + kc * 32];
      u32x4 a1 = *(const u32x4*)&AsmF[buf][afrag0 + 16 * 72 + kc * 32];
#pragma unroll
      for (int nt = 0; nt < 4; ++nt) {
        u32x4 b = *(const u32x4*)(bstep + kc * 8192 + nt * 128);  // global frag
        acc[0][nt] = mfma16(a0, b, acc[0][nt]);
        acc[1][nt] = mfma16(a1, b, acc[1][nt]);
      }
    }
  };

  // prologue: stage step0, issue step1
  i32x4 pa0, pa1, pb0, pb1;
  LOADA(pa0, pa1, 0);
  CONVST(pa0, pa1, stp0);          // one-time exposed latency
  LOADA(pb0, pb1, 1);
  __syncthreads();                 // buf0 = A(0) ready

  // steady state: buf0=A(s) ready, pb holds A(s+1) in flight/arrived
  for (int it = 0; it < 15; ++it) {
    const int s = it * 2;
    LOADA(pa0, pa1, s + 2);        // issue s+2 (consumed one full step later)
    COMPUTE(s, 0);
    CONVST(pb0, pb1, stp1);        // vmcnt waits only for pb (arrived ~1 step ago)
    __syncthreads();               // buf1 = A(s+1) ready; buf0 fully consumed
    LOADA(pb0, pb1, s + 3);
    COMPUTE(s + 1, 1);
    CONVST(pa0, pa1, stp0);        // buf0 <- A(s+2)
    __syncthreads();
  }
  // epilogue: steps 30, 31 (no more loads)
  COMPUTE(30, 0);
  CONVST(pb0, pb1, stp1);
  __syncthreads();
  COMPUTE(31, 1);
  asm volatile("s_nop 7\n\ts_nop 7\n\ts_nop 7");  // MFMA D -> VALU read hazard

  degs[t] = dsum;
  __syncthreads();
  if (t < 32) {
    int sum = 0;
#pragma unroll
    for (int gg = 0; gg < 4; ++gg)
#pragma unroll
      for (int j = 0; j < 8; ++j) sum += degs[gg * 256 + t * 8 + j];
    degrow[t] = (float)sum;
  }
  // combine the 4 groups' partial C tiles (sequential rounds, disjoint lanes)
  for (int gg = 0; gg < 4; ++gg) {
    if (g == gg) {
#pragma unroll
      for (int mt = 0; mt < 2; ++mt)
#pragma unroll
        for (int nt = 0; nt < 4; ++nt)
#pragma unroll
          for (int i = 0; i < 4; ++i) {
            int row = mt * 16 + l16 * 4 + i;
            int col = w4 * 64 + nt * 16 + l15;
            if (gg == 0) Csum[row * 260 + col] = acc[mt][nt][i];
            else         Csum[row * 260 + col] += acc[mt][nt][i];
          }
    }
    __syncthreads();
  }
  // x1 = S/deg -> nxtf (k<256 half), frag-major chunk = (f>>3)*8192 + m
  {
    int rr = t & 31, kc8 = t >> 5;  // 32 rows x 32 feature-octets
    float rd = 1.0f / degrow[rr];
    const float* cp = &Csum[rr * 260 + kc8 * 8];
    u32x4 h;
    h.x = pack2(cp[0] * rd, cp[1] * rd);
    h.y = pack2(cp[2] * rd, cp[3] * rd);
    h.z = pack2(cp[4] * rd, cp[5] * rd);
    h.w = pack2(cp[6] * rd, cp[7] * rd);
    *(u32x4*)(nxtf + ((size_t)kc8 * 8192 + m0 + rr) * 8) = h;
  }
}

// ---- phase 2: out[m, c=kk*256+o] = sum_k nx[m][k] * w_tf[c][k] + bias[o]
// M=8192 K=512 N=768. Zero LDS: both operands loaded as ready frags from the
// frag-major global layouts. Grid (64, 8): M-tile 128, N-tile 96, 4 waves 2x2.
__global__ __launch_bounds__(256) void phase2(const u16* __restrict__ nxtf,
                                              const u16* __restrict__ wtf,
                                              const float* __restrict__ bias,
                                              float* __restrict__ out) {
  const int t = threadIdx.x, l = t & 63, w = t >> 6;
  const int wm = w & 1, wn = w >> 1;
  const int l15 = l & 15, l16 = l >> 4;
  const int m0 = blockIdx.x * 128, c0 = blockIdx.y * 96;
  f32x4 acc[4][3] = {};
  const u16* abase = nxtf + (size_t)l16 * 65536 + (size_t)(m0 + wm * 64 + l15) * 8;
  const u16* bbase = wtf  + (size_t)l16 * 6144  + (size_t)(c0 + wn * 48 + l15) * 8;
  float bv[3];
#pragma unroll
  for (int nt = 0; nt < 3; ++nt) bv[nt] = bias[(c0 + wn * 48 + nt * 16 + l15) & 255];
#pragma unroll 2
  for (int step = 0; step < 16; ++step) {   // K: step*32
    u32x4 a[4], b[3];
#pragma unroll
    for (int mt = 0; mt < 4; ++mt)
      a[mt] = *(const u32x4*)(abase + (size_t)step * 262144 + mt * 128);
#pragma unroll
    for (int nt = 0; nt < 3; ++nt)
      b[nt] = *(const u32x4*)(bbase + (size_t)step * 24576 + nt * 128);
#pragma unroll
    for (int mt = 0; mt < 4; ++mt)
#pragma unroll
      for (int nt = 0; nt < 3; ++nt)
        acc[mt][nt] = mfma16(a[mt], b[nt], acc[mt][nt]);
  }
  asm volatile("s_nop 7\n\ts_nop 7\n\ts_nop 7");
#pragma unroll
  for (int mt = 0; mt < 4; ++mt)
#pragma unroll
    for (int nt = 0; nt < 3; ++nt) {
      int c = c0 + wn * 48 + nt * 16 + l15;
      int kk = c >> 8, o = c & 255;
      float* op = out + (size_t)kk * 2097152 +
                  (size_t)(m0 + wm * 64 + mt * 16 + l16 * 4) * 256 + o;
#pragma unroll
      for (int i = 0; i < 4; ++i)
        __builtin_nontemporal_store(acc[mt][nt][i] + bv[nt], op + (size_t)i * 256);
    }
}

extern "C" void kernel_launch(void* const* d_in, const int* in_sizes, int n_in,
                              void* d_out, int out_size, void* d_ws, size_t ws_size,
                              hipStream_t stream) {
  (void)in_sizes; (void)n_in; (void)out_size; (void)ws_size;
  const float* x    = (const float*)d_in[1];
  const int*   adj  = (const int*)d_in[2];
  const float* wgt  = (const float*)d_in[3];
  const float* bias = (const float*)d_in[4];
  float* out = (float*)d_out;

  char* ws = (char*)d_ws;
  u16* xtf  = (u16*)ws;                      // 4 MB  [256K chunks]
  u16* nxtf = (u16*)(ws + (4u << 20));       // 8 MB  [512K chunks: k<256 from phase1]
  u16* wtf  = (u16*)(ws + (12u << 20));      // 768 KB

  conv_all<<<2240, 256, 0, stream>>>(x, wgt, xtf, nxtf, wtf);
  phase1  <<<256, 1024, 0, stream>>>(adj, xtf, nxtf);
  phase2  <<<dim3(64, 8), 256, 0, stream>>>(nxtf, wtf, bias, out);
}